// Round 8
// baseline (216.927 us; speedup 1.0000x reference)
//
#include <hip/hip_runtime.h>

#define NF 128
#define OUTF 64

// mark bits
#define M2 1
#define M1 2
#define M0 4

// capacity caps (expected ~13 / ~190 / ~2600 nodes; huge slack)
#define CAP_F2 2048
#define CAP_E3 4096
#define CAP_F1 32768
#define CAP_E2 65536
#define CAP_F0 131072
#define CAP_E1 262144

// cnt[0]=F2, cnt[1]=E3, cnt[2]=F1, cnt[3]=E2, cnt[4]=F0, cnt[5]=E1
#define NBLK 256          // 256 blocks x 256 thr; 64KB LDS -> 1/CU, co-resident
#define NBAR 6            // barrier flag arrays (256 ints each)

struct KArgs {
    const float* x;
    const int* srcp;
    const int* dstp;
    int E, n, last;
    const float* W1; const float* b1;
    const float* W2; const float* b2;
    const float* W3; const float* b3;
    const float* fcW; const float* fcb;
    int* deg; int* mark; int* cnt; int* bar;
    int* F2; int2* E3l; int* F1; int2* E2l; int* F0; int2* E1l;
    float* H1; float* H2;
    float* out;
};

// ---------- agent-scope (coherence-point, write-through) helpers ----------
// All cross-block workspace WRITES go through these (or device atomics), so
// L2 never holds dirty workspace lines -> barrier needs invalidate only.
__device__ __forceinline__ void ag_store_i(int* p, int v) {
    __hip_atomic_store(p, v, __ATOMIC_RELAXED, __HIP_MEMORY_SCOPE_AGENT);
}
__device__ __forceinline__ void ag_store_f(float* p, float v) {
    __hip_atomic_store(p, v, __ATOMIC_RELAXED, __HIP_MEMORY_SCOPE_AGENT);
}
__device__ __forceinline__ void ag_store_u64(unsigned long long* p, unsigned long long v) {
    __hip_atomic_store(p, v, __ATOMIC_RELAXED, __HIP_MEMORY_SCOPE_AGENT);
}
__device__ __forceinline__ void ag_store_e(int2* p, int2 v) {
    unsigned long long u = ((unsigned long long)(unsigned)v.y << 32) | (unsigned)v.x;
    ag_store_u64((unsigned long long*)p, u);
}
__device__ __forceinline__ int ag_load_i(const int* p) {
    return __hip_atomic_load((int*)p, __ATOMIC_RELAXED, __HIP_MEMORY_SCOPE_AGENT);
}

// ---- RMW-free all-to-all grid barrier ----
// Arrive: one agent STORE to own flag (no same-line RMW chain).
// Poll: wave 0's 64 lanes read all 256 flags (4 coalesced uncached loads),
// __all-ballot until everyone arrived. Leader's final ACQUIRE load emits the
// L1 invalidate so subsequent cached reads refill fresh (validated r5-r7).
__device__ __forceinline__ void gbar(int* flags) {
    __syncthreads();                       // compiler drains vmcnt per wave
    const int t = threadIdx.x;
    if (t < 64) {
        if (t == 0) {
            asm volatile("s_waitcnt vmcnt(0)" ::: "memory");
            ag_store_i(&flags[blockIdx.x], 1);
        }
        for (;;) {
            int f0 = ag_load_i(&flags[t]);
            int f1 = ag_load_i(&flags[t + 64]);
            int f2 = ag_load_i(&flags[t + 128]);
            int f3 = ag_load_i(&flags[t + 192]);
            if (__all(f0 && f1 && f2 && f3)) break;
            __builtin_amdgcn_s_sleep(1);
        }
        if (t == 0)
            (void)__hip_atomic_load(&flags[0], __ATOMIC_ACQUIRE,
                                    __HIP_MEMORY_SCOPE_AGENT);   // L1 invalidate
    }
    __syncthreads();
}

// ---- per-edge hit handlers ----
__device__ __forceinline__ void p1_hit(const KArgs& a, int d, int i) {
    if (d == a.last) {
        int s = a.srcp[i];
        int p = atomicAdd(&a.cnt[1], 1);
        if (p < CAP_E3) ag_store_e(&a.E3l[p], make_int2(s, d));
        if (!(atomicOr(&a.mark[s], M2) & M2)) {
            int q = atomicAdd(&a.cnt[0], 1);
            if (q < CAP_F2) ag_store_i(&a.F2[q], s);
            int r = atomicAdd(&a.cnt[3], 1);            // self-edge into E2
            if (r < CAP_E2) ag_store_e(&a.E2l[r], make_int2(s, s));
        }
    }
}

__device__ __forceinline__ void p2_hit(const KArgs& a, int d, int i) {
    if (a.mark[d] & M2) {                               // M2 final during P2
        int s = a.srcp[i];
        int p = atomicAdd(&a.cnt[3], 1);
        if (p < CAP_E2) ag_store_e(&a.E2l[p], make_int2(s, d));
        if (!(atomicOr(&a.mark[s], M1) & M1)) {
            int q = atomicAdd(&a.cnt[2], 1);
            if (q < CAP_F1) ag_store_i(&a.F1[q], s);
            int r = atomicAdd(&a.cnt[5], 1);            // self-edge into E1
            if (r < CAP_E1) ag_store_e(&a.E1l[r], make_int2(s, s));
        }
    }
}

__device__ __forceinline__ void p3_hit(const KArgs& a, int d, int i) {
    if (a.mark[d] & M1) {                               // M1 final during P3
        int s = a.srcp[i];
        int p = atomicAdd(&a.cnt[5], 1);
        if (p < CAP_E1) ag_store_e(&a.E1l[p], make_int2(s, d));
        if (!(atomicOr(&a.mark[s], M0) & M0)) {
            int q = atomicAdd(&a.cnt[4], 1);
            if (q < CAP_F0) ag_store_i(&a.F0[q], s);
        }
    }
}

__global__ __launch_bounds__(256, 2) void k_fused(KArgs a)
{
    __shared__ float wsm[128][128];   // 64 KB: W staging; row 0 reused by FC
    const int gtid = blockIdx.x * blockDim.x + threadIdx.x;
    const int gstride = gridDim.x * blockDim.x;
    const int t = threadIdx.x;
    const int wave = t >> 6, lane = t & 63;
    const int E = a.E, n = a.n;
    int* bar = a.bar;
    const bool vec4 = (((uintptr_t)a.dstp & 15) == 0);
    const int4* d4p = (const int4*)a.dstp;
    const int nq = E >> 2;

    // ================= P0: zero deg + mark (replaces 400KB host memset) ======
    {
        unsigned long long* dz = (unsigned long long*)a.deg;
        unsigned long long* mz = (unsigned long long*)a.mark;
        int half = n >> 1;                 // n = 50000, even
        for (int i = gtid; i < half; i += gstride) ag_store_u64(&dz[i], 0ull);
        for (int i = gtid; i < half; i += gstride) ag_store_u64(&mz[i], 0ull);
        if (n & 1) {
            if (gtid == 0) { ag_store_i(&a.deg[n-1], 0); ag_store_i(&a.mark[n-1], 0); }
        }
    }
    gbar(&bar[0 * NBLK]);

    // ================= P1: seed + level-1 scan (dst == last) =================
    if (gtid == 0) {
        if (!(atomicOr(&a.mark[a.last], M2) & M2)) {
            int p = atomicAdd(&a.cnt[0], 1);
            if (p < CAP_F2) ag_store_i(&a.F2[p], a.last);
            int r = atomicAdd(&a.cnt[3], 1);
            if (r < CAP_E2) ag_store_e(&a.E2l[r], make_int2(a.last, a.last));
            int e = atomicAdd(&a.cnt[1], 1);
            if (e < CAP_E3) ag_store_e(&a.E3l[e], make_int2(a.last, a.last));
        }
    }
    if (vec4) {
        for (int q = gtid; q < nq; q += gstride) {
            int4 d4 = d4p[q];
            int i = q << 2;
            p1_hit(a, d4.x, i); p1_hit(a, d4.y, i + 1);
            p1_hit(a, d4.z, i + 2); p1_hit(a, d4.w, i + 3);
        }
        for (int i = (nq << 2) + gtid; i < E; i += gstride) p1_hit(a, a.dstp[i], i);
    } else {
        for (int i = gtid; i < E; i += gstride) p1_hit(a, a.dstp[i], i);
    }
    gbar(&bar[1 * NBLK]);

    // ====== P2: level-2 scan (M2 -> M1) + self-prop F2 -> F1 (+E1 self) ======
    {
        int sc = min(a.cnt[0], CAP_F2);
        for (int i = gtid; i < sc; i += gstride) {
            int v = a.F2[i];
            if (!(atomicOr(&a.mark[v], M1) & M1)) {
                int p = atomicAdd(&a.cnt[2], 1);
                if (p < CAP_F1) ag_store_i(&a.F1[p], v);
                int r = atomicAdd(&a.cnt[5], 1);
                if (r < CAP_E1) ag_store_e(&a.E1l[r], make_int2(v, v));
            }
        }
        if (vec4) {
            for (int q = gtid; q < nq; q += gstride) {
                int4 d4 = d4p[q];
                int i = q << 2;
                p2_hit(a, d4.x, i); p2_hit(a, d4.y, i + 1);
                p2_hit(a, d4.z, i + 2); p2_hit(a, d4.w, i + 3);
            }
            for (int i = (nq << 2) + gtid; i < E; i += gstride) p2_hit(a, a.dstp[i], i);
        } else {
            for (int i = gtid; i < E; i += gstride) p2_hit(a, a.dstp[i], i);
        }
    }
    gbar(&bar[2 * NBLK]);

    // ====== P3: level-3 scan (M1 -> M0) + self-prop F1 -> F0 ======
    {
        int sc = min(a.cnt[2], CAP_F1);
        for (int i = gtid; i < sc; i += gstride) {
            int v = a.F1[i];
            if (!(atomicOr(&a.mark[v], M0) & M0)) {
                int p = atomicAdd(&a.cnt[4], 1);
                if (p < CAP_F0) ag_store_i(&a.F0[p], v);
            }
        }
        if (vec4) {
            for (int q = gtid; q < nq; q += gstride) {
                int4 d4 = d4p[q];
                int i = q << 2;
                p3_hit(a, d4.x, i); p3_hit(a, d4.y, i + 1);
                p3_hit(a, d4.z, i + 2); p3_hit(a, d4.w, i + 3);
            }
            for (int i = (nq << 2) + gtid; i < E; i += gstride) p3_hit(a, a.dstp[i], i);
        } else {
            for (int i = gtid; i < E; i += gstride) p3_hit(a, a.dstp[i], i);
        }
    }
    gbar(&bar[3 * NBLK]);

    // ====== P4: deg scan (marked dsts) + GEMM1: H1 = x @ W1 on F0 rows ======
    {
        if (vec4) {
            for (int q = gtid; q < nq; q += gstride) {
                int4 d4 = d4p[q];
                if (a.mark[d4.x]) atomicAdd(&a.deg[d4.x], 1);
                if (a.mark[d4.y]) atomicAdd(&a.deg[d4.y], 1);
                if (a.mark[d4.z]) atomicAdd(&a.deg[d4.z], 1);
                if (a.mark[d4.w]) atomicAdd(&a.deg[d4.w], 1);
            }
            for (int i = (nq << 2) + gtid; i < E; i += gstride) {
                int d = a.dstp[i];
                if (a.mark[d]) atomicAdd(&a.deg[d], 1);
            }
        } else {
            for (int i = gtid; i < E; i += gstride) {
                int d = a.dstp[i];
                if (a.mark[d]) atomicAdd(&a.deg[d], 1);
            }
        }
        int rows = min(a.cnt[4], CAP_F0);
        if ((int)blockIdx.x * 4 < rows) {
            {   // stage W1
                const float4* W4 = (const float4*)a.W1;
                float4* S4 = (float4*)&wsm[0][0];
                #pragma unroll
                for (int it = 0; it < 16; ++it) S4[it * 256 + t] = W4[it * 256 + t];
            }
            __syncthreads();
            for (int base = blockIdx.x * 4; base < rows; base += gridDim.x * 4) {
                int r = base + wave;
                if (r >= rows) continue;
                int v = a.F0[r];
                size_t off = (size_t)v * NF;
                float x0 = a.x[off + lane];
                float x1 = a.x[off + lane + 64];
                float a0 = 0.f, a1 = 0.f;
                #pragma unroll 16
                for (int k = 0; k < 64; ++k) {
                    float xk = __shfl(x0, k);
                    a0 += xk * wsm[k][lane];
                    a1 += xk * wsm[k][lane + 64];
                }
                #pragma unroll 16
                for (int k = 0; k < 64; ++k) {
                    float xk = __shfl(x1, k);
                    a0 += xk * wsm[k + 64][lane];
                    a1 += xk * wsm[k + 64][lane + 64];
                }
                ag_store_f(&a.H1[off + lane],      a0);
                ag_store_f(&a.H1[off + lane + 64], a1);
            }
        }
    }
    gbar(&bar[4 * NBLK]);

    // ====== P5: GEMM2 with fused E1-gather input (registers, no agg array) ====
    {
        int rows = min(a.cnt[2], CAP_F1);
        int e1cnt = min(a.cnt[5], CAP_E1);
        if ((int)blockIdx.x * 4 < rows) {
            {   // stage W2
                const float4* W4 = (const float4*)a.W2;
                float4* S4 = (float4*)&wsm[0][0];
                #pragma unroll
                for (int it = 0; it < 16; ++it) S4[it * 256 + t] = W4[it * 256 + t];
            }
            __syncthreads();
            for (int base = blockIdx.x * 4; base < rows; base += gridDim.x * 4) {
                int r = base + wave;
                if (r >= rows) continue;          // uniform per wave
                int v = a.F1[r];
                float dv = rsqrtf(1.f + (float)a.deg[v]);
                float x0 = 0.f, x1 = 0.f;
                for (int bb = 0; bb < e1cnt; bb += 64) {
                    int idx = bb + lane;
                    int sx = 0, sy = -1;
                    if (idx < e1cnt) { int2 e = a.E1l[idx]; sx = e.x; sy = e.y; }
                    unsigned long long m = __ballot(sy == v);
                    while (m) {
                        int j = __ffsll(m) - 1;
                        m &= m - 1;
                        int s = __shfl(sx, j);
                        float w = rsqrtf(1.f + (float)a.deg[s]) * dv;
                        size_t so = (size_t)s * NF;
                        x0 += w * a.H1[so + lane];
                        x1 += w * a.H1[so + lane + 64];
                    }
                }
                x0 = fmaxf(x0 + a.b1[lane],      0.f);
                x1 = fmaxf(x1 + a.b1[lane + 64], 0.f);
                float a0 = 0.f, a1 = 0.f;
                #pragma unroll 16
                for (int k = 0; k < 64; ++k) {
                    float xk = __shfl(x0, k);
                    a0 += xk * wsm[k][lane];
                    a1 += xk * wsm[k][lane + 64];
                }
                #pragma unroll 16
                for (int k = 0; k < 64; ++k) {
                    float xk = __shfl(x1, k);
                    a0 += xk * wsm[k + 64][lane];
                    a1 += xk * wsm[k + 64][lane + 64];
                }
                size_t off = (size_t)v * NF;
                ag_store_f(&a.H2[off + lane],      a0);
                ag_store_f(&a.H2[off + lane + 64], a1);
            }
        }
    }
    gbar(&bar[5 * NBLK]);

    // ====== P6 (block 0): E2-gather + GEMM3 + E3-reduce + FC ======
    if (blockIdx.x == 0) {
        {   // stage W3
            const float4* W4 = (const float4*)a.W3;
            float4* S4 = (float4*)&wsm[0][0];
            #pragma unroll
            for (int it = 0; it < 16; ++it) S4[it * 256 + t] = W4[it * 256 + t];
        }
        __syncthreads();
        int rows = min(a.cnt[0], CAP_F2);
        int e2cnt = min(a.cnt[3], CAP_E2);
        for (int r = wave; r < rows; r += 4) {
            int v = a.F2[r];
            float dv = rsqrtf(1.f + (float)a.deg[v]);
            float x0 = 0.f, x1 = 0.f;
            for (int bb = 0; bb < e2cnt; bb += 64) {
                int idx = bb + lane;
                int sx = 0, sy = -1;
                if (idx < e2cnt) { int2 e = a.E2l[idx]; sx = e.x; sy = e.y; }
                unsigned long long m = __ballot(sy == v);
                while (m) {
                    int j = __ffsll(m) - 1;
                    m &= m - 1;
                    int s = __shfl(sx, j);
                    float w = rsqrtf(1.f + (float)a.deg[s]) * dv;
                    size_t so = (size_t)s * NF;
                    x0 += w * a.H2[so + lane];
                    x1 += w * a.H2[so + lane + 64];
                }
            }
            x0 = fmaxf(x0 + a.b2[lane],      0.f);
            x1 = fmaxf(x1 + a.b2[lane + 64], 0.f);
            float a0 = 0.f, a1 = 0.f;
            #pragma unroll 16
            for (int k = 0; k < 64; ++k) {
                float xk = __shfl(x0, k);
                a0 += xk * wsm[k][lane];
                a1 += xk * wsm[k][lane + 64];
            }
            #pragma unroll 16
            for (int k = 0; k < 64; ++k) {
                float xk = __shfl(x1, k);
                a0 += xk * wsm[k + 64][lane];
                a1 += xk * wsm[k + 64][lane + 64];
            }
            size_t off = (size_t)v * NF;
            // H3 stored into H1 buffer (H1 dead now); same-block reads only
            a.H1[off + lane]      = a0;
            a.H1[off + lane + 64] = a1;
        }
        __syncthreads();
        if (t < NF) {
            float dl = rsqrtf(1.f + (float)a.deg[a.last]);
            float acc = 0.f;
            int e3cnt = min(a.cnt[1], CAP_E3);
            for (int i = 0; i < e3cnt; ++i) {
                int s = a.E3l[i].x;
                acc += rsqrtf(1.f + (float)a.deg[s]) * dl * a.H1[(size_t)s * NF + t];
            }
            wsm[0][t] = fmaxf(acc + a.b3[t], 0.f);
        }
        __syncthreads();
        if (t < OUTF) {
            float acc = a.fcb[t];
            #pragma unroll 16
            for (int k = 0; k < NF; ++k) acc += wsm[0][k] * a.fcW[k * OUTF + t];
            a.out[t] = acc;
        }
    }
}

// ---------------------------------------------------------------------------

extern "C" void kernel_launch(void* const* d_in, const int* in_sizes, int n_in,
                              void* d_out, int out_size, void* d_ws, size_t ws_size,
                              hipStream_t stream)
{
    const float* x    = (const float*)d_in[0];
    const int*   ei   = (const int*)d_in[1];
    const float* W1   = (const float*)d_in[2];
    const float* b1   = (const float*)d_in[3];
    const float* W2   = (const float*)d_in[4];
    const float* b2   = (const float*)d_in[5];
    const float* W3   = (const float*)d_in[6];
    const float* b3   = (const float*)d_in[7];
    const float* fcW  = (const float*)d_in[8];
    const float* fcb  = (const float*)d_in[9];
    float* out = (float*)d_out;

    const int n = in_sizes[0] / NF;       // 50000
    const int E = in_sizes[1] / 2;        // 600000
    const int* src = ei;
    const int* dst = ei + E;
    const int last = n - 1;

    char* wp = (char*)d_ws;
    auto alloc = [&](size_t bytes) -> void* {
        void* r = (void*)wp;
        wp += (bytes + 255) & ~(size_t)255;
        return r;
    };
    int*   deg  = (int*)alloc((size_t)n * 4);       // zeroed in-kernel (P0)
    int*   mark = (int*)alloc((size_t)n * 4);       // zeroed in-kernel (P0)
    int*   cnt  = (int*)alloc(64 * 4);              // zeroed by host memset
    int*   bar  = (int*)alloc(NBAR * NBLK * 4);     // zeroed by host memset
    size_t zbytes = (char*)wp - (char*)cnt;         // ~6.4 KB only

    int*   F2   = (int*) alloc(CAP_F2 * 4);
    int2*  E3   = (int2*)alloc(CAP_E3 * 8);
    int*   F1   = (int*) alloc(CAP_F1 * 4);
    int2*  E2   = (int2*)alloc(CAP_E2 * 8);
    int*   F0   = (int*) alloc(CAP_F0 * 4);
    int2*  E1   = (int2*)alloc(CAP_E1 * 8);
    float* H1   = (float*)alloc((size_t)n * NF * 4);
    float* H2   = (float*)alloc((size_t)n * NF * 4);

    KArgs ha;
    ha.x = x; ha.srcp = src; ha.dstp = dst;
    ha.E = E; ha.n = n; ha.last = last;
    ha.W1 = W1; ha.b1 = b1; ha.W2 = W2; ha.b2 = b2;
    ha.W3 = W3; ha.b3 = b3; ha.fcW = fcW; ha.fcb = fcb;
    ha.deg = deg; ha.mark = mark; ha.cnt = cnt; ha.bar = bar;
    ha.F2 = F2; ha.E3l = E3; ha.F1 = F1; ha.E2l = E2; ha.F0 = F0; ha.E1l = E1;
    ha.H1 = H1; ha.H2 = H2; ha.out = out;

    hipMemsetAsync(cnt, 0, zbytes, stream);   // zeros cnt + barrier flags (6.4 KB)

    // Plain (graph-capturable) launch. Co-residency by construction:
    // 64KB LDS -> <=2 blocks/CU; NBLK=256 <= 256 CUs.
    k_fused<<<dim3(NBLK), dim3(256), 0, stream>>>(ha);
}

// Round 9
// 166.493 us; speedup vs baseline: 1.3029x; 1.3029x over previous
//
#include <hip/hip_runtime.h>

#define NF 128
#define OUTF 64

// mark bits
#define M2 1   // layer-2 frontier (in-neighbors of last, + last)
#define M1 2   // layer-1 frontier

// capacity caps (expected ~13 / ~190 / ~2400; huge slack)
#define CAP_F2 2048
#define CAP_E3 4096
#define CAP_F1 32768
#define CAP_E2 65536
#define CAP_E1 262144

// cnt[0]=F2, cnt[1]=E3, cnt[2]=F1, cnt[3]=E2, cnt[5]=E1

// ---------------------------------------------------------------------------
// scan1: unconditional in-degree + level-1 collection (dst == last) + seed
// ---------------------------------------------------------------------------
__global__ void k_scan1(const int* __restrict__ src, const int* __restrict__ dst,
                        int E, int last, int* __restrict__ mark, int* __restrict__ deg,
                        int* __restrict__ cnt, int* __restrict__ F2,
                        int2* __restrict__ E3l, int2* __restrict__ E2l)
{
    const int gtid = blockIdx.x * blockDim.x + threadIdx.x;
    if (gtid == 0) {
        // seed: last joins F2 unconditionally (scan skips s==last)
        atomicOr(&mark[last], M2);
        int q = atomicAdd(&cnt[0], 1);
        if (q < CAP_F2) F2[q] = last;
        int r = atomicAdd(&cnt[3], 1);                 // self-loop edge in E2
        if (r < CAP_E2) E2l[r] = make_int2(last, last);
        int e = atomicAdd(&cnt[1], 1);                 // self-loop edge in E3
        if (e < CAP_E3) E3l[e] = make_int2(last, last);
    }

    auto hit = [&](int d, int i) {
        atomicAdd(&deg[d], 1);                         // in-degree, all nodes
        if (d == last) {
            int s = src[i];
            int p = atomicAdd(&cnt[1], 1);
            if (p < CAP_E3) E3l[p] = make_int2(s, d);
            if (s != last && !(atomicOr(&mark[s], M2) & M2)) {
                int q = atomicAdd(&cnt[0], 1);
                if (q < CAP_F2) F2[q] = s;
                int r = atomicAdd(&cnt[3], 1);         // self-loop edge in E2
                if (r < CAP_E2) E2l[r] = make_int2(s, s);
            }
        }
    };

    const int nq = E >> 2;
    if ((((uintptr_t)dst) & 15) == 0) {
        if (gtid < nq) {
            int4 d4 = ((const int4*)dst)[gtid];
            int i = gtid << 2;
            hit(d4.x, i); hit(d4.y, i + 1); hit(d4.z, i + 2); hit(d4.w, i + 3);
        }
        if (gtid == 0)
            for (int i = nq << 2; i < E; ++i) hit(dst[i], i);
    } else {
        for (int k = 0; k < 4; ++k) {
            int i = gtid * 4 + k;
            if (i < E) hit(dst[i], i);
        }
    }
}

// ---------------------------------------------------------------------------
// scan2: level-2 collection (dst marked M2) + self-prop F2 -> F1 (+E1 selfs)
// ---------------------------------------------------------------------------
__global__ void k_scan2(const int* __restrict__ src, const int* __restrict__ dst,
                        int E, int* __restrict__ mark, int* __restrict__ cnt,
                        const int* __restrict__ F2, int* __restrict__ F1,
                        int2* __restrict__ E2l, int2* __restrict__ E1l)
{
    const int gtid = blockIdx.x * blockDim.x + threadIdx.x;

    {   // self-prop: every F2 member enters F1 (self-loop edge into E1)
        int sc = cnt[0]; if (sc > CAP_F2) sc = CAP_F2;
        if (gtid < sc) {
            int v = F2[gtid];
            if (!(atomicOr(&mark[v], M1) & M1)) {
                int p = atomicAdd(&cnt[2], 1);
                if (p < CAP_F1) F1[p] = v;
                int r = atomicAdd(&cnt[5], 1);
                if (r < CAP_E1) E1l[r] = make_int2(v, v);
            }
        }
    }

    auto hit = [&](int d, int i) {
        if (mark[d] & M2) {
            int s = src[i];
            int p = atomicAdd(&cnt[3], 1);
            if (p < CAP_E2) E2l[p] = make_int2(s, d);
            if (!(atomicOr(&mark[s], M1) & M1)) {
                int q = atomicAdd(&cnt[2], 1);
                if (q < CAP_F1) F1[q] = s;
                int r = atomicAdd(&cnt[5], 1);         // self-loop edge in E1
                if (r < CAP_E1) E1l[r] = make_int2(s, s);
            }
        }
    };

    const int nq = E >> 2;
    if ((((uintptr_t)dst) & 15) == 0) {
        if (gtid < nq) {
            int4 d4 = ((const int4*)dst)[gtid];
            int i = gtid << 2;
            hit(d4.x, i); hit(d4.y, i + 1); hit(d4.z, i + 2); hit(d4.w, i + 3);
        }
        if (gtid == 0)
            for (int i = nq << 2; i < E; ++i) hit(dst[i], i);
    } else {
        for (int k = 0; k < 4; ++k) {
            int i = gtid * 4 + k;
            if (i < E) hit(dst[i], i);
        }
    }
}

// ---------------------------------------------------------------------------
// scan3: level-3 collection (dst marked M1) -> E1; zero AGG1[F1], AGG2[F2]
// ---------------------------------------------------------------------------
__global__ void k_scan3(const int* __restrict__ src, const int* __restrict__ dst,
                        int E, const int* __restrict__ mark, int* __restrict__ cnt,
                        const int* __restrict__ F1, const int* __restrict__ F2,
                        int2* __restrict__ E1l,
                        float* __restrict__ AGG1, float* __restrict__ AGG2)
{
    const int gtid = blockIdx.x * blockDim.x + threadIdx.x;

    {   // zero agg rows (lists final after scan2)
        int f1 = cnt[2]; if (f1 > CAP_F1) f1 = CAP_F1;
        if (gtid < f1 * NF)
            AGG1[(size_t)F1[gtid >> 7] * NF + (gtid & 127)] = 0.f;
        int f2 = cnt[0]; if (f2 > CAP_F2) f2 = CAP_F2;
        if (gtid < f2 * NF)
            AGG2[(size_t)F2[gtid >> 7] * NF + (gtid & 127)] = 0.f;
    }

    auto hit = [&](int d, int i) {
        if (mark[d] & M1) {
            int s = src[i];
            int p = atomicAdd(&cnt[5], 1);
            if (p < CAP_E1) E1l[p] = make_int2(s, d);
        }
    };

    const int nq = E >> 2;
    if ((((uintptr_t)dst) & 15) == 0) {
        if (gtid < nq) {
            int4 d4 = ((const int4*)dst)[gtid];
            int i = gtid << 2;
            hit(d4.x, i); hit(d4.y, i + 1); hit(d4.z, i + 2); hit(d4.w, i + 3);
        }
        if (gtid == 0)
            for (int i = nq << 2; i < E; ++i) hit(dst[i], i);
    } else {
        for (int k = 0; k < 4; ++k) {
            int i = gtid * 4 + k;
            if (i < E) hit(dst[i], i);
        }
    }
}

// ---------------------------------------------------------------------------
// per-edge GEMV + atomic scatter:  AGG[d] += w * (act(Xin[s]) @ W)
// act = relu(x + bias) if bias, else identity. One wave per edge.
// ---------------------------------------------------------------------------
__global__ __launch_bounds__(256) void k_gemv(
    const int2* __restrict__ Elist, const int* __restrict__ cntPtr, int cap,
    const float* __restrict__ Xin, const float* __restrict__ bias,
    const float* __restrict__ W, const int* __restrict__ deg,
    float* __restrict__ AGG)
{
    __shared__ float wsm[128][128];
    int ecnt = *cntPtr; if (ecnt > cap) ecnt = cap;
    if ((int)blockIdx.x * 4 >= ecnt) return;      // block-uniform: no work

    const int t = threadIdx.x;
    {   // stage W (row-major) into LDS
        const float4* W4 = (const float4*)W;
        float4* S4 = (float4*)&wsm[0][0];
        #pragma unroll
        for (int it = 0; it < 16; ++it) S4[it * 256 + t] = W4[it * 256 + t];
    }
    __syncthreads();

    const int wave = t >> 6, lane = t & 63;
    const int wstride = gridDim.x * 4;
    for (int e = blockIdx.x * 4 + wave; e < ecnt; e += wstride) {
        int2 ed = Elist[e];
        float w = rsqrtf(1.f + (float)deg[ed.x]) * rsqrtf(1.f + (float)deg[ed.y]);
        size_t so = (size_t)ed.x * NF;
        float x0 = Xin[so + lane];
        float x1 = Xin[so + lane + 64];
        if (bias) {
            x0 = fmaxf(x0 + bias[lane],      0.f);
            x1 = fmaxf(x1 + bias[lane + 64], 0.f);
        }
        float a0 = 0.f, a1 = 0.f;
        #pragma unroll 16
        for (int k = 0; k < 64; ++k) {
            float xk = __shfl(x0, k);
            a0 += xk * wsm[k][lane];
            a1 += xk * wsm[k][lane + 64];
        }
        #pragma unroll 16
        for (int k = 0; k < 64; ++k) {
            float xk = __shfl(x1, k);
            a0 += xk * wsm[k + 64][lane];
            a1 += xk * wsm[k + 64][lane + 64];
        }
        size_t off = (size_t)ed.y * NF;
        atomicAdd(&AGG[off + lane],      w * a0);
        atomicAdd(&AGG[off + lane + 64], w * a1);
    }
}

// ---------------------------------------------------------------------------
// tail (1 block): per-E3-edge GEMV with relu(AGG2[s]+b2) @ W3, register
// accumulate (all dst == last), then relu(+b3) and FC.
// ---------------------------------------------------------------------------
__global__ __launch_bounds__(256) void k_tail(
    const int2* __restrict__ E3l, const int* __restrict__ cntPtr, int cap,
    const float* __restrict__ AGG2, const float* __restrict__ b2,
    const float* __restrict__ W3, const float* __restrict__ b3,
    const float* __restrict__ fcW, const float* __restrict__ fcb,
    const int* __restrict__ deg, int last, float* __restrict__ out)
{
    __shared__ float wsm[128][128];
    const int t = threadIdx.x;
    {   // stage W3
        const float4* W4 = (const float4*)W3;
        float4* S4 = (float4*)&wsm[0][0];
        #pragma unroll
        for (int it = 0; it < 16; ++it) S4[it * 256 + t] = W4[it * 256 + t];
    }
    __syncthreads();

    const int wave = t >> 6, lane = t & 63;
    int e3 = *cntPtr; if (e3 > cap) e3 = cap;
    const float dl = rsqrtf(1.f + (float)deg[last]);

    float acc0 = 0.f, acc1 = 0.f;
    for (int e = wave; e < e3; e += 4) {
        int s = E3l[e].x;
        float w = rsqrtf(1.f + (float)deg[s]) * dl;
        size_t so = (size_t)s * NF;
        float x0 = fmaxf(AGG2[so + lane]      + b2[lane],      0.f);
        float x1 = fmaxf(AGG2[so + lane + 64] + b2[lane + 64], 0.f);
        float a0 = 0.f, a1 = 0.f;
        #pragma unroll 16
        for (int k = 0; k < 64; ++k) {
            float xk = __shfl(x0, k);
            a0 += xk * wsm[k][lane];
            a1 += xk * wsm[k][lane + 64];
        }
        #pragma unroll 16
        for (int k = 0; k < 64; ++k) {
            float xk = __shfl(x1, k);
            a0 += xk * wsm[k + 64][lane];
            a1 += xk * wsm[k + 64][lane + 64];
        }
        acc0 += w * a0;
        acc1 += w * a1;
    }
    __syncthreads();                     // all waves done reading W3
    wsm[wave][lane]      = acc0;         // reuse W3 rows 0..3 as reduce buffer
    wsm[wave][lane + 64] = acc1;
    __syncthreads();
    if (t < NF) {
        float s4 = wsm[0][t] + wsm[1][t] + wsm[2][t] + wsm[3][t];
        wsm[8][t] = fmaxf(s4 + b3[t], 0.f);
    }
    __syncthreads();
    if (t < OUTF) {
        float acc = fcb[t];
        #pragma unroll 16
        for (int k = 0; k < NF; ++k) acc += wsm[8][k] * fcW[k * OUTF + t];
        out[t] = acc;
    }
}

// ---------------------------------------------------------------------------

extern "C" void kernel_launch(void* const* d_in, const int* in_sizes, int n_in,
                              void* d_out, int out_size, void* d_ws, size_t ws_size,
                              hipStream_t stream)
{
    const float* x    = (const float*)d_in[0];
    const int*   ei   = (const int*)d_in[1];
    const float* W1   = (const float*)d_in[2];
    const float* b1   = (const float*)d_in[3];
    const float* W2   = (const float*)d_in[4];
    const float* b2   = (const float*)d_in[5];
    const float* W3   = (const float*)d_in[6];
    const float* b3   = (const float*)d_in[7];
    const float* fcW  = (const float*)d_in[8];
    const float* fcb  = (const float*)d_in[9];
    float* out = (float*)d_out;

    const int n = in_sizes[0] / NF;       // 50000
    const int E = in_sizes[1] / 2;        // 600000
    const int* src = ei;
    const int* dst = ei + E;
    const int last = n - 1;

    char* wp = (char*)d_ws;
    auto alloc = [&](size_t bytes) -> void* {
        void* r = (void*)wp;
        wp += (bytes + 255) & ~(size_t)255;
        return r;
    };
    // zeroed region: deg | mark | cnt  (one memset, ~400KB)
    int*   deg  = (int*)alloc((size_t)n * 4);
    int*   mark = (int*)alloc((size_t)n * 4);
    int*   cnt  = (int*)alloc(64 * 4);
    size_t zbytes = (char*)wp - (char*)deg;

    int*   F2   = (int*) alloc(CAP_F2 * 4);
    int2*  E3   = (int2*)alloc(CAP_E3 * 8);
    int*   F1   = (int*) alloc(CAP_F1 * 4);
    int2*  E2   = (int2*)alloc(CAP_E2 * 8);
    int2*  E1   = (int2*)alloc(CAP_E1 * 8);
    float* AGG1 = (float*)alloc((size_t)n * NF * 4);
    float* AGG2 = (float*)alloc((size_t)n * NF * 4);

    hipMemsetAsync(deg, 0, zbytes, stream);

    // scans: one int4 (4 edges) per thread
    const int B = 256;
    const int SB = ((E + 3) / 4 + B - 1) / B;

    k_scan1<<<SB, B, 0, stream>>>(src, dst, E, last, mark, deg, cnt, F2, E3, E2);
    k_scan2<<<SB, B, 0, stream>>>(src, dst, E, mark, cnt, F2, F1, E2, E1);
    k_scan3<<<SB, B, 0, stream>>>(src, dst, E, mark, cnt, F1, F2, E1, AGG1, AGG2);

    // per-edge GEMV scatters (wave per edge)
    k_gemv<<<256, B, 0, stream>>>(E1, &cnt[5], CAP_E1, x, nullptr, W1, deg, AGG1);
    k_gemv<<<64,  B, 0, stream>>>(E2, &cnt[3], CAP_E2, AGG1, b1, W2, deg, AGG2);

    // layer 3 + FC in one block
    k_tail<<<1, B, 0, stream>>>(E3, &cnt[1], CAP_E3, AGG2, b2, W3, b3,
                                fcW, fcb, deg, last, out);
}